// Round 18
// baseline (302.880 us; speedup 1.0000x reference)
//
#include <hip/hip_runtime.h>
#include <hip/hip_bf16.h>

#define B_ 64
#define L_ 512
#define H_ 1024
#define A_ 1024

typedef short bf16x8 __attribute__((ext_vector_type(8)));
typedef float f32x4 __attribute__((ext_vector_type(4)));

__device__ __forceinline__ void gld16(const void* g, void* l) {
  __builtin_amdgcn_global_load_lds((const __attribute__((address_space(1))) void*)g,
                                   (__attribute__((address_space(3))) void*)l, 16, 0, 0);
}

__device__ __forceinline__ unsigned short f2bf(float f) {
  unsigned u = __builtin_bit_cast(unsigned, f);
  u = (u + 0x7fffu + ((u >> 16) & 1u)) >> 16;
  return (unsigned short)u;
}

__device__ __forceinline__ unsigned short cvtbf(float f) {
  __hip_bfloat16 b = __float2bfloat16(f);
  return __builtin_bit_cast(unsigned short, b);
}

__device__ __forceinline__ float fast_tanh(float x) {
  float e = __expf(2.f * x);
  float r = __builtin_amdgcn_rcpf(e + 1.f);
  return __builtin_fmaf(-2.f, r, 1.f);
}

// ---------- K0: Wt[a][h] = bf16(W[h][a]) ----------
__global__ __launch_bounds__(256) void wtrans_kernel(const float* __restrict__ W,
                                                     unsigned short* __restrict__ Wt) {
  __shared__ float tile[32][33];
  int tx = threadIdx.x & 31, ty = threadIdx.x >> 5;
  int a0 = (blockIdx.x & 31) << 5, h0 = (blockIdx.x >> 5) << 5;
#pragma unroll
  for (int i = 0; i < 4; ++i) {
    int h = ty + i * 8;
    tile[h][tx] = W[(size_t)(h0 + h) * A_ + a0 + tx];
  }
  __syncthreads();
#pragma unroll
  for (int i = 0; i < 4; ++i) {
    int a = ty + i * 8;
    Wt[(size_t)(a0 + a) * H_ + h0 + tx] = f2bf(tile[tx][a]);
  }
}

// ====== 8-phase conveyor (R14 schedule) with REG-STAGED f32 A-operand ======
// A: f32 global->reg issued in phases 0-1 (AISSUE), cvt_pk + ds_write + 
//    lgkmcnt(0) AFTER the MFMA of phases 2-3 (AWRITE) -> consumed phases 4-7
//    (>=1 barrier after publish). Compiler's auto-vmcnt for the rA regs
//    drains exactly the A-f32 loads (FIFO oldest), leaving B's gld16 counted.
// B: unchanged proven gld16 path; ckpt vmcnt(4) at ph3/ph7 keeps B(next)
//    in flight across the K-tile boundary (R14 semantics preserved).
#define STG_B(buf, h, kt) {                                                 \
    gld16(gB##h    + (kt) * 64, &Bs[buf][(h) * 8192 + lofs]);               \
    gld16(gB##h##b + (kt) * 64, &Bs[buf][(h) * 8192 + 4096 + lofs]); }

#define AISSUE(SET, kt) {                                                   \
    const float* p0 = gAf##SET  + (kt) * 64;                                \
    const float* p1 = gAf##SET##b + (kt) * 64;                              \
    rA##SET##_0 = ((const float4*)p0)[0]; rA##SET##_1 = ((const float4*)p0)[1]; \
    rA##SET##_2 = ((const float4*)p1)[0]; rA##SET##_3 = ((const float4*)p1)[1]; }

#define AWRITE(SET, buf) {                                                  \
    bf16x8 v0, v1;                                                          \
    v0[0] = (short)cvtbf(rA##SET##_0.x); v0[1] = (short)cvtbf(rA##SET##_0.y); \
    v0[2] = (short)cvtbf(rA##SET##_0.z); v0[3] = (short)cvtbf(rA##SET##_0.w); \
    v0[4] = (short)cvtbf(rA##SET##_1.x); v0[5] = (short)cvtbf(rA##SET##_1.y); \
    v0[6] = (short)cvtbf(rA##SET##_1.z); v0[7] = (short)cvtbf(rA##SET##_1.w); \
    v1[0] = (short)cvtbf(rA##SET##_2.x); v1[1] = (short)cvtbf(rA##SET##_2.y); \
    v1[2] = (short)cvtbf(rA##SET##_2.z); v1[3] = (short)cvtbf(rA##SET##_2.w); \
    v1[4] = (short)cvtbf(rA##SET##_3.x); v1[5] = (short)cvtbf(rA##SET##_3.y); \
    v1[6] = (short)cvtbf(rA##SET##_3.z); v1[7] = (short)cvtbf(rA##SET##_3.w); \
    *(bf16x8*)&As[buf][(SET) * 8192 + lofs] = v0;                           \
    *(bf16x8*)&As[buf][(SET) * 8192 + 4096 + lofs] = v1;                    \
    asm volatile("s_waitcnt lgkmcnt(0)" ::: "memory"); }

#define LOAD_BQ(buf) { _Pragma("unroll") for (int ni = 0; ni < 4; ++ni) {   \
    int brow = wc * 64 + ni * 16 + l15;                                     \
    bq[ni][0] = *(const bf16x8*)&Bs[buf][brow * 64 + rd0];                  \
    bq[ni][1] = *(const bf16x8*)&Bs[buf][brow * 64 + rd1]; } }

// phase: {A ds_reads | PRE_OP -> barrier -> 16 MFMA -> POST_OP -> [ckpt] -> barrier}
#define PHASE(q, buf, PRE_OP, POST_OP, CKPT) {                              \
    bf16x8 aq0, aq1, aq2, aq3;                                              \
    { int ar = wr * 128 + (q) * 32 + l15;                                   \
      aq0 = *(const bf16x8*)&As[buf][ar * 64 + rd0];                        \
      aq1 = *(const bf16x8*)&As[buf][ar * 64 + rd1];                        \
      aq2 = *(const bf16x8*)&As[buf][(ar + 16) * 64 + rd0];                 \
      aq3 = *(const bf16x8*)&As[buf][(ar + 16) * 64 + rd1]; }               \
    PRE_OP;                                                                 \
    asm volatile("s_barrier" ::: "memory");                                 \
    __builtin_amdgcn_s_setprio(1);                                          \
    _Pragma("unroll") for (int ni = 0; ni < 4; ++ni) {                      \
      acc[(q)*2][ni] = __builtin_amdgcn_mfma_f32_16x16x32_bf16(             \
          aq0, bq[ni][0], acc[(q)*2][ni], 0, 0, 0);                         \
      acc[(q)*2][ni] = __builtin_amdgcn_mfma_f32_16x16x32_bf16(             \
          aq1, bq[ni][1], acc[(q)*2][ni], 0, 0, 0);                         \
      acc[(q)*2+1][ni] = __builtin_amdgcn_mfma_f32_16x16x32_bf16(           \
          aq2, bq[ni][0], acc[(q)*2+1][ni], 0, 0, 0);                       \
      acc[(q)*2+1][ni] = __builtin_amdgcn_mfma_f32_16x16x32_bf16(           \
          aq3, bq[ni][1], acc[(q)*2+1][ni], 0, 0, 0); }                     \
    __builtin_amdgcn_s_setprio(0);                                          \
    POST_OP;                                                                \
    if (CKPT) asm volatile("s_waitcnt vmcnt(4)" ::: "memory");              \
    asm volatile("s_barrier" ::: "memory"); }

#define CONV_ITER_F(kt1, kt2, kt3) {                                        \
    LOAD_BQ(0);                                                             \
    PHASE(0, 0, AISSUE(0, kt1), ;, 0);                                      \
    PHASE(1, 0, AISSUE(1, kt1), ;, 0);                                      \
    PHASE(2, 0, STG_B(0, 0, kt2), AWRITE(0, 1), 0);                         \
    PHASE(3, 0, STG_B(0, 1, kt2), AWRITE(1, 1), 1);                         \
    LOAD_BQ(1);                                                             \
    PHASE(0, 1, AISSUE(0, kt2), ;, 0);                                      \
    PHASE(1, 1, AISSUE(1, kt2), ;, 0);                                      \
    PHASE(2, 1, STG_B(1, 0, kt3), AWRITE(0, 0), 0);                         \
    PHASE(3, 1, STG_B(1, 1, kt3), AWRITE(1, 0), 1); }

// ---------- K1: 256x256 8-phase fused proj: Pb = bf16(tanh(X@Wt^T)[*diag]) --
__global__ __launch_bounds__(512, 2) void proj8_kernel(
    const float* __restrict__ Xlt, const float* __restrict__ Xrt,
    const unsigned short* __restrict__ Wt, const float* __restrict__ diag,
    unsigned short* __restrict__ Pb) {
  __shared__ unsigned short As[2][256 * 64];
  __shared__ unsigned short Bs[2][256 * 64];
  int t = threadIdx.x;
  int lane = t & 63, wave = t >> 6;
  int wr = wave >> 2, wc = wave & 3;
  int l15 = lane & 15, l4 = lane >> 4;

  int bid = (int)blockIdx.x;           // 1024 blocks, XCD swizzle
  int x = bid & 7, k = bid >> 3;
  int mt = x + 8 * (k >> 2);           // [0,256)
  int nt = k & 3;
  int mrow0 = mt << 8, ncol0 = nt << 8;
  int isLt = (mt < 128);
  const float* X = isLt ? Xlt : Xrt;
  int xrow0 = (isLt ? mt : mt - 128) << 8;

  int rs = t >> 3, ss = t & 7;
  // A source: f32, pre-swizzled chunk (8 f32 per 16B-bf16 chunk slot)
  const float* gAf0  = X + (size_t)(xrow0 + rs) * H_ + ((ss ^ (rs & 7)) * 8);
  const float* gAf0b = gAf0 + (size_t)64 * H_;
  const float* gAf1  = gAf0 + (size_t)128 * H_;
  const float* gAf1b = gAf0 + (size_t)192 * H_;
  const unsigned short* gB0 = Wt + (size_t)(ncol0 + rs) * H_ + ((ss ^ (rs & 7)) << 3);
  const unsigned short* gB0b = gB0 + (size_t)64 * H_;
  const unsigned short* gB1  = gB0 + (size_t)128 * H_;
  const unsigned short* gB1b = gB0 + (size_t)192 * H_;
  int lofs = (rs * 8 + ss) * 8;

  int rd0 = (l4 ^ (l15 & 7)) * 8;
  int rd1 = ((4 + l4) ^ (l15 & 7)) * 8;

  f32x4 acc[8][4] = {};
  bf16x8 bq[4][2];
  float4 rA0_0, rA0_1, rA0_2, rA0_3;
  float4 rA1_0, rA1_1, rA1_2, rA1_3;

  // prologue: A(kt0)->reg->As[0]; B(kt0)->Bs[0]; B(kt1)->Bs[1] in flight
  AISSUE(0, 0); AISSUE(1, 0);
  STG_B(0, 0, 0); STG_B(0, 1, 0);
  AWRITE(0, 0); AWRITE(1, 0);
  STG_B(1, 0, 1); STG_B(1, 1, 1);
  asm volatile("s_waitcnt vmcnt(4)" ::: "memory");  // B(kt0) landed
  asm volatile("s_barrier" ::: "memory");

  CONV_ITER_F(1, 2, 3)    CONV_ITER_F(3, 4, 5)    CONV_ITER_F(5, 6, 7)
  CONV_ITER_F(7, 8, 9)    CONV_ITER_F(9, 10, 11)  CONV_ITER_F(11, 12, 13)
  CONV_ITER_F(13, 14, 15) CONV_ITER_F(15, 0, 1)

#pragma unroll
  for (int mi = 0; mi < 8; ++mi) {
#pragma unroll
    for (int ni = 0; ni < 4; ++ni) {
      int col = ncol0 + wc * 64 + ni * 16 + l15;
      float d = isLt ? diag[col] : 1.0f;
#pragma unroll
      for (int rr = 0; rr < 4; ++rr) {
        int row = mrow0 + wr * 128 + mi * 16 + l4 * 4 + rr;
        Pb[(size_t)row * A_ + col] = f2bf(fast_tanh(acc[mi][ni][rr]) * d);
      }
    }
  }
}

// ---------- K2: fused score+softmax (R17, proven) ----------
__global__ __launch_bounds__(512) void ssmax_kernel(
    const unsigned short* __restrict__ Pb,
    const float* __restrict__ mask_lt, const float* __restrict__ mask_rt,
    float* __restrict__ out) {
  __shared__ unsigned short As2[3][128 * 32];  // 3 x 8 KB
  __shared__ unsigned short Bs2[3][512 * 32];  // 3 x 32 KB
  int t = threadIdx.x;
  int lane = t & 63, wave = t >> 6;
  int wr = wave >> 2, wc = wave & 3;
  int l15 = lane & 15, l4 = lane >> 4;

  int bid = (int)blockIdx.x;           // 256 blocks
  int g = (bid & 7) * 32 + (bid >> 3);
  int b = g >> 2, mt = g & 3;

  int arow0 = b * L_ + mt * 128;
  int brow0 = B_ * L_ + b * L_;

  int ra = t >> 2, ca = t & 3;
  const unsigned short* gA = Pb + (size_t)(arow0 + ra) * H_ + ((ca ^ ((ra >> 1) & 3)) << 3);
  const unsigned short* gBu0; const unsigned short* gBu1;
  const unsigned short* gBu2; const unsigned short* gBu3;
  int bd0, bd1, bd2, bd3;
  {
    int ci, r, c;
    ci = t;        r = ci >> 2; c = ci & 3;
    gBu0 = Pb + (size_t)(brow0 + r) * H_ + ((c ^ ((r >> 1) & 3)) << 3); bd0 = ci * 8;
    ci = 512 + t;  r = ci >> 2; c = ci & 3;
    gBu1 = Pb + (size_t)(brow0 + r) * H_ + ((c ^ ((r >> 1) & 3)) << 3); bd1 = ci * 8;
    ci = 1024 + t; r = ci >> 2; c = ci & 3;
    gBu2 = Pb + (size_t)(brow0 + r) * H_ + ((c ^ ((r >> 1) & 3)) << 3); bd2 = ci * 8;
    ci = 1536 + t; r = ci >> 2; c = ci & 3;
    gBu3 = Pb + (size_t)(brow0 + r) * H_ + ((c ^ ((r >> 1) & 3)) << 3); bd3 = ci * 8;
  }
  int rd = (l4 ^ ((l15 >> 1) & 3)) * 8;

#define SSTG_B01(buf, kt_) { int ko = (kt_) * 32;                  \
    gld16(gBu0 + ko, &Bs2[buf][bd0]); gld16(gBu1 + ko, &Bs2[buf][bd1]); }
#define SSTG_B23A(buf, kt_) { int ko = (kt_) * 32;                 \
    gld16(gBu2 + ko, &Bs2[buf][bd2]); gld16(gBu3 + ko, &Bs2[buf][bd3]); \
    gld16(gA + ko, &As2[buf][t * 8]); }

  f32x4 acc[4][8] = {};

  SSTG_B01(0, 0); SSTG_B23A(0, 0);
  SSTG_B01(1, 1); SSTG_B23A(1, 1);
  asm volatile("s_waitcnt vmcnt(5)" ::: "memory");
  asm volatile("s_barrier" ::: "memory");

#pragma unroll 1
  for (int j = 0; j < 32; ++j) {
    int buf = j - (j / 3) * 3;
    int nb = buf + 2; if (nb >= 3) nb -= 3;
    bool st = (j <= 29);
    const unsigned short* Ac = As2[buf];
    const unsigned short* Bc = Bs2[buf];

    bf16x8 aq[4], bq[4];
#pragma unroll
    for (int mi = 0; mi < 4; ++mi)
      aq[mi] = *(const bf16x8*)&Ac[(wr * 64 + mi * 16 + l15) * 32 + rd];
#pragma unroll
    for (int ni = 0; ni < 4; ++ni)
      bq[ni] = *(const bf16x8*)&Bc[(wc * 128 + ni * 16 + l15) * 32 + rd];
    if (st) SSTG_B01(nb, j + 2);
    asm volatile("s_barrier" ::: "memory");
    __builtin_amdgcn_s_setprio(1);
#pragma unroll
    for (int mi = 0; mi < 4; ++mi)
#pragma unroll
      for (int ni = 0; ni < 4; ++ni)
        acc[mi][ni] = __builtin_amdgcn_mfma_f32_16x16x32_bf16(aq[mi], bq[ni], acc[mi][ni], 0, 0, 0);
    __builtin_amdgcn_s_setprio(0);
    asm volatile("s_barrier" ::: "memory");

#pragma unroll
    for (int ni = 0; ni < 4; ++ni)
      bq[ni] = *(const bf16x8*)&Bc[(wc * 128 + 64 + ni * 16 + l15) * 32 + rd];
    if (st) SSTG_B23A(nb, j + 2);
    asm volatile("s_barrier" ::: "memory");
    __builtin_amdgcn_s_setprio(1);
#pragma unroll
    for (int mi = 0; mi < 4; ++mi)
#pragma unroll
      for (int ni = 0; ni < 4; ++ni)
        acc[mi][ni + 4] = __builtin_amdgcn_mfma_f32_16x16x32_bf16(aq[mi], bq[ni], acc[mi][ni + 4], 0, 0, 0);
    __builtin_amdgcn_s_setprio(0);
    if (j < 30)
      asm volatile("s_waitcnt vmcnt(5)" ::: "memory");
    else
      asm volatile("s_waitcnt vmcnt(0)" ::: "memory");
    asm volatile("s_barrier" ::: "memory");
  }
#undef SSTG_B01
#undef SSTG_B23A

  float* red = (float*)&As2[0][0];
  float* red2 = red + 512;

  float ml[4][4];
#pragma unroll
  for (int mi = 0; mi < 4; ++mi)
#pragma unroll
    for (int rr = 0; rr < 4; ++rr)
      ml[mi][rr] = mask_lt[b * L_ + mt * 128 + wr * 64 + mi * 16 + l4 * 4 + rr];
  float mr[8];
#pragma unroll
  for (int ni = 0; ni < 8; ++ni)
    mr[ni] = mask_rt[b * L_ + wc * 128 + ni * 16 + l15];

#pragma unroll
  for (int mi = 0; mi < 4; ++mi)
#pragma unroll
    for (int ni = 0; ni < 8; ++ni)
#pragma unroll
      for (int rr = 0; rr < 4; ++rr)
        acc[mi][ni][rr] *= ml[mi][rr] * mr[ni];

#pragma unroll
  for (int mi = 0; mi < 4; ++mi)
#pragma unroll
    for (int rr = 0; rr < 4; ++rr) {
      float m = acc[mi][0][rr];
#pragma unroll
      for (int ni = 1; ni < 8; ++ni) m = fmaxf(m, acc[mi][ni][rr]);
      m = fmaxf(m, __shfl_xor(m, 1));
      m = fmaxf(m, __shfl_xor(m, 2));
      m = fmaxf(m, __shfl_xor(m, 4));
      m = fmaxf(m, __shfl_xor(m, 8));
      if (l15 == 0) red[(wr * 64 + mi * 16 + l4 * 4 + rr) * 4 + wc] = m;
    }
  __syncthreads();
  float mfull[4][4];
#pragma unroll
  for (int mi = 0; mi < 4; ++mi)
#pragma unroll
    for (int rr = 0; rr < 4; ++rr) {
      float4 v = *(const float4*)&red[(wr * 64 + mi * 16 + l4 * 4 + rr) * 4];
      mfull[mi][rr] = fmaxf(fmaxf(v.x, v.y), fmaxf(v.z, v.w));
    }

#pragma unroll
  for (int mi = 0; mi < 4; ++mi)
#pragma unroll
    for (int rr = 0; rr < 4; ++rr) {
      float s = 0.f;
#pragma unroll
      for (int ni = 0; ni < 8; ++ni) {
        float e = __expf(acc[mi][ni][rr] - mfull[mi][rr]);
        acc[mi][ni][rr] = e;
        s += e;
      }
      s += __shfl_xor(s, 1);
      s += __shfl_xor(s, 2);
      s += __shfl_xor(s, 4);
      s += __shfl_xor(s, 8);
      if (l15 == 0) red2[(wr * 64 + mi * 16 + l4 * 4 + rr) * 4 + wc] = s;
    }
  __syncthreads();

  float* obase = out + (size_t)b * L_ * L_ + (size_t)(mt * 128) * L_;
#pragma unroll
  for (int mi = 0; mi < 4; ++mi)
#pragma unroll
    for (int rr = 0; rr < 4; ++rr) {
      int row = wr * 64 + mi * 16 + l4 * 4 + rr;
      float4 v = *(const float4*)&red2[row * 4];
      float inv = 1.0f / (((v.x + v.y) + (v.z + v.w)));
      float scale = inv * ml[mi][rr];
#pragma unroll
      for (int ni = 0; ni < 8; ++ni) {
        int col = wc * 128 + ni * 16 + l15;
        obase[(size_t)row * L_ + col] = acc[mi][ni][rr] * scale * mr[ni];
      }
    }
}

extern "C" void kernel_launch(void* const* d_in, const int* in_sizes, int n_in,
                              void* d_out, int out_size, void* d_ws, size_t ws_size,
                              hipStream_t stream) {
  const float* reps_lt = (const float*)d_in[0];
  const float* reps_rt = (const float*)d_in[1];
  const float* mask_lt = (const float*)d_in[2];
  const float* mask_rt = (const float*)d_in[3];
  const float* attn_w1 = (const float*)d_in[4];
  const float* diag    = (const float*)d_in[5];
  float* out = (float*)d_out;

  unsigned short* wt = (unsigned short*)d_ws;           // 2 MB
  unsigned short* pb = wt + (size_t)H_ * A_;            // 128 MB

  hipLaunchKernelGGL(wtrans_kernel, dim3(1024), dim3(256), 0, stream, attn_w1, wt);
  hipLaunchKernelGGL(proj8_kernel, dim3(1024), dim3(512), 0, stream,
                     reps_lt, reps_rt, wt, diag, pb);
  hipLaunchKernelGGL(ssmax_kernel, dim3(256), dim3(512), 0, stream,
                     pb, mask_lt, mask_rt, out);
}

// Round 19
// 290.165 us; speedup vs baseline: 1.0438x; 1.0438x over previous
//
#include <hip/hip_runtime.h>
#include <hip/hip_bf16.h>

#define B_ 64
#define L_ 512
#define H_ 1024
#define A_ 1024

typedef short bf16x8 __attribute__((ext_vector_type(8)));
typedef float f32x4 __attribute__((ext_vector_type(4)));

__device__ __forceinline__ void gld16(const void* g, void* l) {
  __builtin_amdgcn_global_load_lds((const __attribute__((address_space(1))) void*)g,
                                   (__attribute__((address_space(3))) void*)l, 16, 0, 0);
}

__device__ __forceinline__ unsigned short f2bf(float f) {
  unsigned u = __builtin_bit_cast(unsigned, f);
  u = (u + 0x7fffu + ((u >> 16) & 1u)) >> 16;
  return (unsigned short)u;
}

__device__ __forceinline__ unsigned short cvtbf(float f) {
  __hip_bfloat16 b = __float2bfloat16(f);
  return __builtin_bit_cast(unsigned short, b);
}

__device__ __forceinline__ float fast_tanh(float x) {
  float e = __expf(2.f * x);
  float r = __builtin_amdgcn_rcpf(e + 1.f);
  return __builtin_fmaf(-2.f, r, 1.f);
}

// ---------- K-1: Xb = bf16(concat(Xlt, Xrt)), streaming ----------
// Branch-free: grid 8192x256 = 2M threads, 4M chunks/tensor -> each thread
// does exactly 2 lt + 2 rt chunks (stride 2M). Nontemporal stores keep the
// 128MB write stream out of L2 (no reuse at this scale).
__device__ __forceinline__ void cvt_chunk(const float* __restrict__ src,
                                          unsigned short* __restrict__ dst) {
  float4 v0 = ((const float4*)src)[0];
  float4 v1 = ((const float4*)src)[1];
  bf16x8 o;
  o[0] = (short)cvtbf(v0.x); o[1] = (short)cvtbf(v0.y);
  o[2] = (short)cvtbf(v0.z); o[3] = (short)cvtbf(v0.w);
  o[4] = (short)cvtbf(v1.x); o[5] = (short)cvtbf(v1.y);
  o[6] = (short)cvtbf(v1.z); o[7] = (short)cvtbf(v1.w);
  __builtin_nontemporal_store(o, (bf16x8*)dst);
}

__global__ __launch_bounds__(256) void cvt_kernel(const float* __restrict__ lt,
                                                  const float* __restrict__ rt,
                                                  unsigned short* __restrict__ xb) {
  const size_t NC = (size_t)B_ * L_ * H_ / 8;   // 4M chunks per tensor
  const size_t S  = NC / 2;                     // 2M = thread count
  size_t c0 = (size_t)blockIdx.x * 256 + threadIdx.x;  // [0, 2M)
  cvt_chunk(lt + c0 * 8,        xb + c0 * 8);
  cvt_chunk(lt + (c0 + S) * 8,  xb + (c0 + S) * 8);
  cvt_chunk(rt + c0 * 8,        xb + (NC + c0) * 8);
  cvt_chunk(rt + (c0 + S) * 8,  xb + (NC + c0 + S) * 8);
}

// ---------- K0: Wt[a][h] = bf16(W[h][a]) ----------
__global__ __launch_bounds__(256) void wtrans_kernel(const float* __restrict__ W,
                                                     unsigned short* __restrict__ Wt) {
  __shared__ float tile[32][33];
  int tx = threadIdx.x & 31, ty = threadIdx.x >> 5;
  int a0 = (blockIdx.x & 31) << 5, h0 = (blockIdx.x >> 5) << 5;
#pragma unroll
  for (int i = 0; i < 4; ++i) {
    int h = ty + i * 8;
    tile[h][tx] = W[(size_t)(h0 + h) * A_ + a0 + tx];
  }
  __syncthreads();
#pragma unroll
  for (int i = 0; i < 4; ++i) {
    int a = ty + i * 8;
    Wt[(size_t)(a0 + a) * H_ + h0 + tx] = f2bf(tile[tx][a]);
  }
}

// ================= 8-phase conveyor (R14/R17, proven) =======================
#define STG_A(buf, h, kt) {                                                 \
    gld16(gA##h    + (kt) * 64, &As[buf][(h) * 8192 + lofs]);               \
    gld16(gA##h##b + (kt) * 64, &As[buf][(h) * 8192 + 4096 + lofs]); }
#define STG_B(buf, h, kt) {                                                 \
    gld16(gB##h    + (kt) * 64, &Bs[buf][(h) * 8192 + lofs]);               \
    gld16(gB##h##b + (kt) * 64, &Bs[buf][(h) * 8192 + 4096 + lofs]); }

#define LOAD_BQ(buf) { _Pragma("unroll") for (int ni = 0; ni < 4; ++ni) {   \
    int brow = wc * 64 + ni * 16 + l15;                                     \
    bq[ni][0] = *(const bf16x8*)&Bs[buf][brow * 64 + rd0];                  \
    bq[ni][1] = *(const bf16x8*)&Bs[buf][brow * 64 + rd1]; } }

#define PHASE(q, buf, STAGE_OP, CKPT) {                                     \
    bf16x8 aq0, aq1, aq2, aq3;                                              \
    { int ar = wr * 128 + (q) * 32 + l15;                                   \
      aq0 = *(const bf16x8*)&As[buf][ar * 64 + rd0];                        \
      aq1 = *(const bf16x8*)&As[buf][ar * 64 + rd1];                        \
      aq2 = *(const bf16x8*)&As[buf][(ar + 16) * 64 + rd0];                 \
      aq3 = *(const bf16x8*)&As[buf][(ar + 16) * 64 + rd1]; }               \
    STAGE_OP;                                                               \
    asm volatile("s_barrier" ::: "memory");                                 \
    __builtin_amdgcn_s_setprio(1);                                          \
    _Pragma("unroll") for (int ni = 0; ni < 4; ++ni) {                      \
      acc[(q)*2][ni] = __builtin_amdgcn_mfma_f32_16x16x32_bf16(             \
          aq0, bq[ni][0], acc[(q)*2][ni], 0, 0, 0);                         \
      acc[(q)*2][ni] = __builtin_amdgcn_mfma_f32_16x16x32_bf16(             \
          aq1, bq[ni][1], acc[(q)*2][ni], 0, 0, 0);                         \
      acc[(q)*2+1][ni] = __builtin_amdgcn_mfma_f32_16x16x32_bf16(           \
          aq2, bq[ni][0], acc[(q)*2+1][ni], 0, 0, 0);                       \
      acc[(q)*2+1][ni] = __builtin_amdgcn_mfma_f32_16x16x32_bf16(           \
          aq3, bq[ni][1], acc[(q)*2+1][ni], 0, 0, 0); }                     \
    __builtin_amdgcn_s_setprio(0);                                          \
    if (CKPT) asm volatile("s_waitcnt vmcnt(4)" ::: "memory");              \
    asm volatile("s_barrier" ::: "memory"); }

#define CONV_ITER(kt1, kt2, kt3) {                                          \
    LOAD_BQ(0);                                                             \
    PHASE(0, 0, STG_A(1, 0, kt1), 0);                                       \
    PHASE(1, 0, STG_A(1, 1, kt1), 0);                                       \
    PHASE(2, 0, STG_B(0, 0, kt2), 0);                                       \
    PHASE(3, 0, STG_B(0, 1, kt2), 1);                                       \
    LOAD_BQ(1);                                                             \
    PHASE(0, 1, STG_A(0, 0, kt2), 0);                                       \
    PHASE(1, 1, STG_A(0, 1, kt2), 0);                                       \
    PHASE(2, 1, STG_B(1, 0, kt3), 0);                                       \
    PHASE(3, 1, STG_B(1, 1, kt3), 1); }

#define CONVEYOR_LIT()                                                      \
  STG_B(0, 0, 0); STG_B(0, 1, 0);                                           \
  STG_A(0, 0, 0); STG_A(0, 1, 0);                                           \
  STG_B(1, 0, 1); STG_B(1, 1, 1);                                           \
  asm volatile("s_waitcnt vmcnt(4)" ::: "memory");                          \
  asm volatile("s_barrier" ::: "memory");                                   \
  CONV_ITER(1, 2, 3)   CONV_ITER(3, 4, 5)   CONV_ITER(5, 6, 7)              \
  CONV_ITER(7, 8, 9)   CONV_ITER(9, 10, 11) CONV_ITER(11, 12, 13)           \
  CONV_ITER(13, 14, 15) CONV_ITER(15, 0, 1)

// ---------- K1: 256x256 8-phase proj: Pb = bf16(tanh(Xb@Wt^T)[*diag]) ------
__global__ __launch_bounds__(512, 2) void proj8_kernel(
    const unsigned short* __restrict__ Xb, const unsigned short* __restrict__ Wt,
    const float* __restrict__ diag, unsigned short* __restrict__ Pb) {
  __shared__ unsigned short As[2][256 * 64];
  __shared__ unsigned short Bs[2][256 * 64];
  int t = threadIdx.x;
  int lane = t & 63, wave = t >> 6;
  int wr = wave >> 2, wc = wave & 3;
  int l15 = lane & 15, l4 = lane >> 4;

  int bid = (int)blockIdx.x;           // 1024 blocks, XCD swizzle
  int x = bid & 7, k = bid >> 3;
  int mt = x + 8 * (k >> 2);           // [0,256)
  int nt = k & 3;
  int mrow0 = mt << 8, ncol0 = nt << 8;
  int isLt = (mt < 128);

  int rs = t >> 3, ss = t & 7;
  const unsigned short* gA0 = Xb + (size_t)(mrow0 + rs) * H_ + ((ss ^ (rs & 7)) << 3);
  const unsigned short* gA0b = gA0 + (size_t)64 * H_;
  const unsigned short* gA1  = gA0 + (size_t)128 * H_;
  const unsigned short* gA1b = gA0 + (size_t)192 * H_;
  const unsigned short* gB0 = Wt + (size_t)(ncol0 + rs) * H_ + ((ss ^ (rs & 7)) << 3);
  const unsigned short* gB0b = gB0 + (size_t)64 * H_;
  const unsigned short* gB1  = gB0 + (size_t)128 * H_;
  const unsigned short* gB1b = gB0 + (size_t)192 * H_;
  int lofs = (rs * 8 + ss) * 8;

  int rd0 = (l4 ^ (l15 & 7)) * 8;
  int rd1 = ((4 + l4) ^ (l15 & 7)) * 8;

  f32x4 acc[8][4] = {};
  bf16x8 bq[4][2];

  CONVEYOR_LIT();

#pragma unroll
  for (int mi = 0; mi < 8; ++mi) {
#pragma unroll
    for (int ni = 0; ni < 4; ++ni) {
      int col = ncol0 + wc * 64 + ni * 16 + l15;
      float d = isLt ? diag[col] : 1.0f;
#pragma unroll
      for (int rr = 0; rr < 4; ++rr) {
        int row = mrow0 + wr * 128 + mi * 16 + l4 * 4 + rr;
        Pb[(size_t)row * A_ + col] = f2bf(fast_tanh(acc[mi][ni][rr]) * d);
      }
    }
  }
}

// ---------- K2: fused score+softmax (R17, proven) ----------
__global__ __launch_bounds__(512) void ssmax_kernel(
    const unsigned short* __restrict__ Pb,
    const float* __restrict__ mask_lt, const float* __restrict__ mask_rt,
    float* __restrict__ out) {
  __shared__ unsigned short As2[3][128 * 32];  // 3 x 8 KB
  __shared__ unsigned short Bs2[3][512 * 32];  // 3 x 32 KB
  int t = threadIdx.x;
  int lane = t & 63, wave = t >> 6;
  int wr = wave >> 2, wc = wave & 3;
  int l15 = lane & 15, l4 = lane >> 4;

  int bid = (int)blockIdx.x;           // 256 blocks
  int g = (bid & 7) * 32 + (bid >> 3);
  int b = g >> 2, mt = g & 3;

  int arow0 = b * L_ + mt * 128;
  int brow0 = B_ * L_ + b * L_;

  int ra = t >> 2, ca = t & 3;
  const unsigned short* gA = Pb + (size_t)(arow0 + ra) * H_ + ((ca ^ ((ra >> 1) & 3)) << 3);
  const unsigned short* gBu0; const unsigned short* gBu1;
  const unsigned short* gBu2; const unsigned short* gBu3;
  int bd0, bd1, bd2, bd3;
  {
    int ci, r, c;
    ci = t;        r = ci >> 2; c = ci & 3;
    gBu0 = Pb + (size_t)(brow0 + r) * H_ + ((c ^ ((r >> 1) & 3)) << 3); bd0 = ci * 8;
    ci = 512 + t;  r = ci >> 2; c = ci & 3;
    gBu1 = Pb + (size_t)(brow0 + r) * H_ + ((c ^ ((r >> 1) & 3)) << 3); bd1 = ci * 8;
    ci = 1024 + t; r = ci >> 2; c = ci & 3;
    gBu2 = Pb + (size_t)(brow0 + r) * H_ + ((c ^ ((r >> 1) & 3)) << 3); bd2 = ci * 8;
    ci = 1536 + t; r = ci >> 2; c = ci & 3;
    gBu3 = Pb + (size_t)(brow0 + r) * H_ + ((c ^ ((r >> 1) & 3)) << 3); bd3 = ci * 8;
  }
  int rd = (l4 ^ ((l15 >> 1) & 3)) * 8;

#define SSTG_B01(buf, kt_) { int ko = (kt_) * 32;                  \
    gld16(gBu0 + ko, &Bs2[buf][bd0]); gld16(gBu1 + ko, &Bs2[buf][bd1]); }
#define SSTG_B23A(buf, kt_) { int ko = (kt_) * 32;                 \
    gld16(gBu2 + ko, &Bs2[buf][bd2]); gld16(gBu3 + ko, &Bs2[buf][bd3]); \
    gld16(gA + ko, &As2[buf][t * 8]); }

  f32x4 acc[4][8] = {};

  SSTG_B01(0, 0); SSTG_B23A(0, 0);
  SSTG_B01(1, 1); SSTG_B23A(1, 1);
  asm volatile("s_waitcnt vmcnt(5)" ::: "memory");
  asm volatile("s_barrier" ::: "memory");

#pragma unroll 1
  for (int j = 0; j < 32; ++j) {
    int buf = j - (j / 3) * 3;
    int nb = buf + 2; if (nb >= 3) nb -= 3;
    bool st = (j <= 29);
    const unsigned short* Ac = As2[buf];
    const unsigned short* Bc = Bs2[buf];

    bf16x8 aq[4], bq[4];
#pragma unroll
    for (int mi = 0; mi < 4; ++mi)
      aq[mi] = *(const bf16x8*)&Ac[(wr * 64 + mi * 16 + l15) * 32 + rd];
#pragma unroll
    for (int ni = 0; ni < 4; ++ni)
      bq[ni] = *(const bf16x8*)&Bc[(wc * 128 + ni * 16 + l15) * 32 + rd];
    if (st) SSTG_B01(nb, j + 2);
    asm volatile("s_barrier" ::: "memory");
    __builtin_amdgcn_s_setprio(1);
#pragma unroll
    for (int mi = 0; mi < 4; ++mi)
#pragma unroll
      for (int ni = 0; ni < 4; ++ni)
        acc[mi][ni] = __builtin_amdgcn_mfma_f32_16x16x32_bf16(aq[mi], bq[ni], acc[mi][ni], 0, 0, 0);
    __builtin_amdgcn_s_setprio(0);
    asm volatile("s_barrier" ::: "memory");

#pragma unroll
    for (int ni = 0; ni < 4; ++ni)
      bq[ni] = *(const bf16x8*)&Bc[(wc * 128 + 64 + ni * 16 + l15) * 32 + rd];
    if (st) SSTG_B23A(nb, j + 2);
    asm volatile("s_barrier" ::: "memory");
    __builtin_amdgcn_s_setprio(1);
#pragma unroll
    for (int mi = 0; mi < 4; ++mi)
#pragma unroll
      for (int ni = 0; ni < 4; ++ni)
        acc[mi][ni + 4] = __builtin_amdgcn_mfma_f32_16x16x32_bf16(aq[mi], bq[ni], acc[mi][ni + 4], 0, 0, 0);
    __builtin_amdgcn_s_setprio(0);
    if (j < 30)
      asm volatile("s_waitcnt vmcnt(5)" ::: "memory");
    else
      asm volatile("s_waitcnt vmcnt(0)" ::: "memory");
    asm volatile("s_barrier" ::: "memory");
  }
#undef SSTG_B01
#undef SSTG_B23A

  float* red = (float*)&As2[0][0];
  float* red2 = red + 512;

  float ml[4][4];
#pragma unroll
  for (int mi = 0; mi < 4; ++mi)
#pragma unroll
    for (int rr = 0; rr < 4; ++rr)
      ml[mi][rr] = mask_lt[b * L_ + mt * 128 + wr * 64 + mi * 16 + l4 * 4 + rr];
  float mr[8];
#pragma unroll
  for (int ni = 0; ni < 8; ++ni)
    mr[ni] = mask_rt[b * L_ + wc * 128 + ni * 16 + l15];

#pragma unroll
  for (int mi = 0; mi < 4; ++mi)
#pragma unroll
    for (int ni = 0; ni < 8; ++ni)
#pragma unroll
      for (int rr = 0; rr < 4; ++rr)
        acc[mi][ni][rr] *= ml[mi][rr] * mr[ni];

#pragma unroll
  for (int mi = 0; mi < 4; ++mi)
#pragma unroll
    for (int rr = 0; rr < 4; ++rr) {
      float m = acc[mi][0][rr];
#pragma unroll
      for (int ni = 1; ni < 8; ++ni) m = fmaxf(m, acc[mi][ni][rr]);
      m = fmaxf(m, __shfl_xor(m, 1));
      m = fmaxf(m, __shfl_xor(m, 2));
      m = fmaxf(m, __shfl_xor(m, 4));
      m = fmaxf(m, __shfl_xor(m, 8));
      if (l15 == 0) red[(wr * 64 + mi * 16 + l4 * 4 + rr) * 4 + wc] = m;
    }
  __syncthreads();
  float mfull[4][4];
#pragma unroll
  for (int mi = 0; mi < 4; ++mi)
#pragma unroll
    for (int rr = 0; rr < 4; ++rr) {
      float4 v = *(const float4*)&red[(wr * 64 + mi * 16 + l4 * 4 + rr) * 4];
      mfull[mi][rr] = fmaxf(fmaxf(v.x, v.y), fmaxf(v.z, v.w));
    }

#pragma unroll
  for (int mi = 0; mi < 4; ++mi)
#pragma unroll
    for (int rr = 0; rr < 4; ++rr) {
      float s = 0.f;
#pragma unroll
      for (int ni = 0; ni < 8; ++ni) {
        float e = __expf(acc[mi][ni][rr] - mfull[mi][rr]);
        acc[mi][ni][rr] = e;
        s += e;
      }
      s += __shfl_xor(s, 1);
      s += __shfl_xor(s, 2);
      s += __shfl_xor(s, 4);
      s += __shfl_xor(s, 8);
      if (l15 == 0) red2[(wr * 64 + mi * 16 + l4 * 4 + rr) * 4 + wc] = s;
    }
  __syncthreads();

  float* obase = out + (size_t)b * L_ * L_ + (size_t)(mt * 128) * L_;
#pragma unroll
  for (int mi = 0; mi < 4; ++mi)
#pragma unroll
    for (int rr = 0; rr < 4; ++rr) {
      int row = wr * 64 + mi * 16 + l4 * 4 + rr;
      float4 v = *(const float4*)&red2[row * 4];
      float inv = 1.0f / (((v.x + v.y) + (v.z + v.w)));
      float scale = inv * ml[mi][rr];
#pragma unroll
      for (int ni = 0; ni < 8; ++ni) {
        int col = wc * 128 + ni * 16 + l15;
        obase[(size_t)row * L_ + col] = acc[mi][ni][rr] * scale * mr[ni];
      }
    }
}

extern "C" void kernel_launch(void* const* d_in, const int* in_sizes, int n_in,
                              void* d_out, int out_size, void* d_ws, size_t ws_size,
                              hipStream_t stream) {
  const float* reps_lt = (const float*)d_in[0];
  const float* reps_rt = (const float*)d_in[1];
  const float* mask_lt = (const float*)d_in[2];
  const float* mask_rt = (const float*)d_in[3];
  const float* attn_w1 = (const float*)d_in[4];
  const float* diag    = (const float*)d_in[5];
  float* out = (float*)d_out;

  unsigned short* wt = (unsigned short*)d_ws;           // 2 MB
  unsigned short* pb = wt + (size_t)H_ * A_;            // 128 MB
  unsigned short* xb = pb + (size_t)B_ * L_ * A_ * 2;   // 128 MB

  hipLaunchKernelGGL(wtrans_kernel, dim3(1024), dim3(256), 0, stream, attn_w1, wt);
  hipLaunchKernelGGL(cvt_kernel, dim3(8192), dim3(256), 0, stream,
                     reps_lt, reps_rt, xb);
  hipLaunchKernelGGL(proj8_kernel, dim3(1024), dim3(512), 0, stream,
                     xb, wt, diag, pb);
  hipLaunchKernelGGL(ssmax_kernel, dim3(256), dim3(512), 0, stream,
                     pb, mask_lt, mask_rt, out);
}

// Round 20
// 283.511 us; speedup vs baseline: 1.0683x; 1.0235x over previous
//
#include <hip/hip_runtime.h>
#include <hip/hip_bf16.h>

#define B_ 64
#define L_ 512
#define H_ 1024
#define A_ 1024

typedef short bf16x8 __attribute__((ext_vector_type(8)));
typedef float f32x4 __attribute__((ext_vector_type(4)));

__device__ __forceinline__ void gld16(const void* g, void* l) {
  __builtin_amdgcn_global_load_lds((const __attribute__((address_space(1))) void*)g,
                                   (__attribute__((address_space(3))) void*)l, 16, 0, 0);
}

__device__ __forceinline__ unsigned short f2bf(float f) {
  unsigned u = __builtin_bit_cast(unsigned, f);
  u = (u + 0x7fffu + ((u >> 16) & 1u)) >> 16;
  return (unsigned short)u;
}

__device__ __forceinline__ unsigned short cvtbf(float f) {
  __hip_bfloat16 b = __float2bfloat16(f);
  return __builtin_bit_cast(unsigned short, b);
}

__device__ __forceinline__ float fast_tanh(float x) {
  float e = __expf(2.f * x);
  float r = __builtin_amdgcn_rcpf(e + 1.f);
  return __builtin_fmaf(-2.f, r, 1.f);
}

// ---------- K-1: Xb = bf16(concat(Xlt, Xrt)), streaming ----------
// Branch-free: 2M threads, each exactly 2 lt + 2 rt chunks. REGULAR stores:
// xb is consumed by proj8 right after -> L3 handoff matters (R19 lesson:
// nontemporal stores here cost ~9us).
__device__ __forceinline__ void cvt_chunk(const float* __restrict__ src,
                                          unsigned short* __restrict__ dst) {
  float4 v0 = ((const float4*)src)[0];
  float4 v1 = ((const float4*)src)[1];
  bf16x8 o;
  o[0] = (short)cvtbf(v0.x); o[1] = (short)cvtbf(v0.y);
  o[2] = (short)cvtbf(v0.z); o[3] = (short)cvtbf(v0.w);
  o[4] = (short)cvtbf(v1.x); o[5] = (short)cvtbf(v1.y);
  o[6] = (short)cvtbf(v1.z); o[7] = (short)cvtbf(v1.w);
  *(bf16x8*)dst = o;
}

__global__ __launch_bounds__(256) void cvt_kernel(const float* __restrict__ lt,
                                                  const float* __restrict__ rt,
                                                  unsigned short* __restrict__ xb) {
  const size_t NC = (size_t)B_ * L_ * H_ / 8;   // 4M chunks per tensor
  const size_t S  = NC / 2;                     // 2M = thread count
  size_t c0 = (size_t)blockIdx.x * 256 + threadIdx.x;  // [0, 2M)
  cvt_chunk(lt + c0 * 8,        xb + c0 * 8);
  cvt_chunk(lt + (c0 + S) * 8,  xb + (c0 + S) * 8);
  cvt_chunk(rt + c0 * 8,        xb + (NC + c0) * 8);
  cvt_chunk(rt + (c0 + S) * 8,  xb + (NC + c0 + S) * 8);
}

// ---------- K0: Wt[a][h] = bf16(W[h][a]) ----------
__global__ __launch_bounds__(256) void wtrans_kernel(const float* __restrict__ W,
                                                     unsigned short* __restrict__ Wt) {
  __shared__ float tile[32][33];
  int tx = threadIdx.x & 31, ty = threadIdx.x >> 5;
  int a0 = (blockIdx.x & 31) << 5, h0 = (blockIdx.x >> 5) << 5;
#pragma unroll
  for (int i = 0; i < 4; ++i) {
    int h = ty + i * 8;
    tile[h][tx] = W[(size_t)(h0 + h) * A_ + a0 + tx];
  }
  __syncthreads();
#pragma unroll
  for (int i = 0; i < 4; ++i) {
    int a = ty + i * 8;
    Wt[(size_t)(a0 + a) * H_ + h0 + tx] = f2bf(tile[tx][a]);
  }
}

// ================= 8-phase conveyor (R14/R17, proven) =======================
#define STG_A(buf, h, kt) {                                                 \
    gld16(gA##h    + (kt) * 64, &As[buf][(h) * 8192 + lofs]);               \
    gld16(gA##h##b + (kt) * 64, &As[buf][(h) * 8192 + 4096 + lofs]); }
#define STG_B(buf, h, kt) {                                                 \
    gld16(gB##h    + (kt) * 64, &Bs[buf][(h) * 8192 + lofs]);               \
    gld16(gB##h##b + (kt) * 64, &Bs[buf][(h) * 8192 + 4096 + lofs]); }

#define LOAD_BQ(buf) { _Pragma("unroll") for (int ni = 0; ni < 4; ++ni) {   \
    int brow = wc * 64 + ni * 16 + l15;                                     \
    bq[ni][0] = *(const bf16x8*)&Bs[buf][brow * 64 + rd0];                  \
    bq[ni][1] = *(const bf16x8*)&Bs[buf][brow * 64 + rd1]; } }

#define PHASE(q, buf, STAGE_OP, CKPT) {                                     \
    bf16x8 aq0, aq1, aq2, aq3;                                              \
    { int ar = wr * 128 + (q) * 32 + l15;                                   \
      aq0 = *(const bf16x8*)&As[buf][ar * 64 + rd0];                        \
      aq1 = *(const bf16x8*)&As[buf][ar * 64 + rd1];                        \
      aq2 = *(const bf16x8*)&As[buf][(ar + 16) * 64 + rd0];                 \
      aq3 = *(const bf16x8*)&As[buf][(ar + 16) * 64 + rd1]; }               \
    STAGE_OP;                                                               \
    asm volatile("s_barrier" ::: "memory");                                 \
    __builtin_amdgcn_s_setprio(1);                                          \
    _Pragma("unroll") for (int ni = 0; ni < 4; ++ni) {                      \
      acc[(q)*2][ni] = __builtin_amdgcn_mfma_f32_16x16x32_bf16(             \
          aq0, bq[ni][0], acc[(q)*2][ni], 0, 0, 0);                         \
      acc[(q)*2][ni] = __builtin_amdgcn_mfma_f32_16x16x32_bf16(             \
          aq1, bq[ni][1], acc[(q)*2][ni], 0, 0, 0);                         \
      acc[(q)*2+1][ni] = __builtin_amdgcn_mfma_f32_16x16x32_bf16(           \
          aq2, bq[ni][0], acc[(q)*2+1][ni], 0, 0, 0);                       \
      acc[(q)*2+1][ni] = __builtin_amdgcn_mfma_f32_16x16x32_bf16(           \
          aq3, bq[ni][1], acc[(q)*2+1][ni], 0, 0, 0); }                     \
    __builtin_amdgcn_s_setprio(0);                                          \
    if (CKPT) asm volatile("s_waitcnt vmcnt(4)" ::: "memory");              \
    asm volatile("s_barrier" ::: "memory"); }

#define CONV_ITER(kt1, kt2, kt3) {                                          \
    LOAD_BQ(0);                                                             \
    PHASE(0, 0, STG_A(1, 0, kt1), 0);                                       \
    PHASE(1, 0, STG_A(1, 1, kt1), 0);                                       \
    PHASE(2, 0, STG_B(0, 0, kt2), 0);                                       \
    PHASE(3, 0, STG_B(0, 1, kt2), 1);                                       \
    LOAD_BQ(1);                                                             \
    PHASE(0, 1, STG_A(0, 0, kt2), 0);                                       \
    PHASE(1, 1, STG_A(0, 1, kt2), 0);                                       \
    PHASE(2, 1, STG_B(1, 0, kt3), 0);                                       \
    PHASE(3, 1, STG_B(1, 1, kt3), 1); }

#define CONVEYOR_LIT()                                                      \
  STG_B(0, 0, 0); STG_B(0, 1, 0);                                           \
  STG_A(0, 0, 0); STG_A(0, 1, 0);                                           \
  STG_B(1, 0, 1); STG_B(1, 1, 1);                                           \
  asm volatile("s_waitcnt vmcnt(4)" ::: "memory");                          \
  asm volatile("s_barrier" ::: "memory");                                   \
  CONV_ITER(1, 2, 3)   CONV_ITER(3, 4, 5)   CONV_ITER(5, 6, 7)              \
  CONV_ITER(7, 8, 9)   CONV_ITER(9, 10, 11) CONV_ITER(11, 12, 13)           \
  CONV_ITER(13, 14, 15) CONV_ITER(15, 0, 1)

// ---------- K1: 256x256 8-phase proj: Pb = bf16(tanh(Xb@Wt^T)[*diag]) ------
__global__ __launch_bounds__(512, 2) void proj8_kernel(
    const unsigned short* __restrict__ Xb, const unsigned short* __restrict__ Wt,
    const float* __restrict__ diag, unsigned short* __restrict__ Pb) {
  __shared__ unsigned short As[2][256 * 64];
  __shared__ unsigned short Bs[2][256 * 64];
  int t = threadIdx.x;
  int lane = t & 63, wave = t >> 6;
  int wr = wave >> 2, wc = wave & 3;
  int l15 = lane & 15, l4 = lane >> 4;

  int bid = (int)blockIdx.x;           // 1024 blocks, XCD swizzle
  int x = bid & 7, k = bid >> 3;
  int mt = x + 8 * (k >> 2);           // [0,256)
  int nt = k & 3;
  int mrow0 = mt << 8, ncol0 = nt << 8;
  int isLt = (mt < 128);

  int rs = t >> 3, ss = t & 7;
  const unsigned short* gA0 = Xb + (size_t)(mrow0 + rs) * H_ + ((ss ^ (rs & 7)) << 3);
  const unsigned short* gA0b = gA0 + (size_t)64 * H_;
  const unsigned short* gA1  = gA0 + (size_t)128 * H_;
  const unsigned short* gA1b = gA0 + (size_t)192 * H_;
  const unsigned short* gB0 = Wt + (size_t)(ncol0 + rs) * H_ + ((ss ^ (rs & 7)) << 3);
  const unsigned short* gB0b = gB0 + (size_t)64 * H_;
  const unsigned short* gB1  = gB0 + (size_t)128 * H_;
  const unsigned short* gB1b = gB0 + (size_t)192 * H_;
  int lofs = (rs * 8 + ss) * 8;

  int rd0 = (l4 ^ (l15 & 7)) * 8;
  int rd1 = ((4 + l4) ^ (l15 & 7)) * 8;

  f32x4 acc[8][4] = {};
  bf16x8 bq[4][2];

  CONVEYOR_LIT();

#pragma unroll
  for (int mi = 0; mi < 8; ++mi) {
#pragma unroll
    for (int ni = 0; ni < 4; ++ni) {
      int col = ncol0 + wc * 64 + ni * 16 + l15;
      float d = isLt ? diag[col] : 1.0f;
#pragma unroll
      for (int rr = 0; rr < 4; ++rr) {
        int row = mrow0 + wr * 128 + mi * 16 + l4 * 4 + rr;
        Pb[(size_t)row * A_ + col] = f2bf(fast_tanh(acc[mi][ni][rr]) * d);
      }
    }
  }
}

// ---------- K2: fused score+softmax (R17, proven) ----------
__global__ __launch_bounds__(512) void ssmax_kernel(
    const unsigned short* __restrict__ Pb,
    const float* __restrict__ mask_lt, const float* __restrict__ mask_rt,
    float* __restrict__ out) {
  __shared__ unsigned short As2[3][128 * 32];  // 3 x 8 KB
  __shared__ unsigned short Bs2[3][512 * 32];  // 3 x 32 KB
  int t = threadIdx.x;
  int lane = t & 63, wave = t >> 6;
  int wr = wave >> 2, wc = wave & 3;
  int l15 = lane & 15, l4 = lane >> 4;

  int bid = (int)blockIdx.x;           // 256 blocks
  int g = (bid & 7) * 32 + (bid >> 3);
  int b = g >> 2, mt = g & 3;

  int arow0 = b * L_ + mt * 128;
  int brow0 = B_ * L_ + b * L_;

  int ra = t >> 2, ca = t & 3;
  const unsigned short* gA = Pb + (size_t)(arow0 + ra) * H_ + ((ca ^ ((ra >> 1) & 3)) << 3);
  const unsigned short* gBu0; const unsigned short* gBu1;
  const unsigned short* gBu2; const unsigned short* gBu3;
  int bd0, bd1, bd2, bd3;
  {
    int ci, r, c;
    ci = t;        r = ci >> 2; c = ci & 3;
    gBu0 = Pb + (size_t)(brow0 + r) * H_ + ((c ^ ((r >> 1) & 3)) << 3); bd0 = ci * 8;
    ci = 512 + t;  r = ci >> 2; c = ci & 3;
    gBu1 = Pb + (size_t)(brow0 + r) * H_ + ((c ^ ((r >> 1) & 3)) << 3); bd1 = ci * 8;
    ci = 1024 + t; r = ci >> 2; c = ci & 3;
    gBu2 = Pb + (size_t)(brow0 + r) * H_ + ((c ^ ((r >> 1) & 3)) << 3); bd2 = ci * 8;
    ci = 1536 + t; r = ci >> 2; c = ci & 3;
    gBu3 = Pb + (size_t)(brow0 + r) * H_ + ((c ^ ((r >> 1) & 3)) << 3); bd3 = ci * 8;
  }
  int rd = (l4 ^ ((l15 >> 1) & 3)) * 8;

#define SSTG_B01(buf, kt_) { int ko = (kt_) * 32;                  \
    gld16(gBu0 + ko, &Bs2[buf][bd0]); gld16(gBu1 + ko, &Bs2[buf][bd1]); }
#define SSTG_B23A(buf, kt_) { int ko = (kt_) * 32;                 \
    gld16(gBu2 + ko, &Bs2[buf][bd2]); gld16(gBu3 + ko, &Bs2[buf][bd3]); \
    gld16(gA + ko, &As2[buf][t * 8]); }

  f32x4 acc[4][8] = {};

  SSTG_B01(0, 0); SSTG_B23A(0, 0);
  SSTG_B01(1, 1); SSTG_B23A(1, 1);
  asm volatile("s_waitcnt vmcnt(5)" ::: "memory");
  asm volatile("s_barrier" ::: "memory");

#pragma unroll 1
  for (int j = 0; j < 32; ++j) {
    int buf = j - (j / 3) * 3;
    int nb = buf + 2; if (nb >= 3) nb -= 3;
    bool st = (j <= 29);
    const unsigned short* Ac = As2[buf];
    const unsigned short* Bc = Bs2[buf];

    bf16x8 aq[4], bq[4];
#pragma unroll
    for (int mi = 0; mi < 4; ++mi)
      aq[mi] = *(const bf16x8*)&Ac[(wr * 64 + mi * 16 + l15) * 32 + rd];
#pragma unroll
    for (int ni = 0; ni < 4; ++ni)
      bq[ni] = *(const bf16x8*)&Bc[(wc * 128 + ni * 16 + l15) * 32 + rd];
    if (st) SSTG_B01(nb, j + 2);
    asm volatile("s_barrier" ::: "memory");
    __builtin_amdgcn_s_setprio(1);
#pragma unroll
    for (int mi = 0; mi < 4; ++mi)
#pragma unroll
      for (int ni = 0; ni < 4; ++ni)
        acc[mi][ni] = __builtin_amdgcn_mfma_f32_16x16x32_bf16(aq[mi], bq[ni], acc[mi][ni], 0, 0, 0);
    __builtin_amdgcn_s_setprio(0);
    asm volatile("s_barrier" ::: "memory");

#pragma unroll
    for (int ni = 0; ni < 4; ++ni)
      bq[ni] = *(const bf16x8*)&Bc[(wc * 128 + 64 + ni * 16 + l15) * 32 + rd];
    if (st) SSTG_B23A(nb, j + 2);
    asm volatile("s_barrier" ::: "memory");
    __builtin_amdgcn_s_setprio(1);
#pragma unroll
    for (int mi = 0; mi < 4; ++mi)
#pragma unroll
      for (int ni = 0; ni < 4; ++ni)
        acc[mi][ni + 4] = __builtin_amdgcn_mfma_f32_16x16x32_bf16(aq[mi], bq[ni], acc[mi][ni + 4], 0, 0, 0);
    __builtin_amdgcn_s_setprio(0);
    if (j < 30)
      asm volatile("s_waitcnt vmcnt(5)" ::: "memory");
    else
      asm volatile("s_waitcnt vmcnt(0)" ::: "memory");
    asm volatile("s_barrier" ::: "memory");
  }
#undef SSTG_B01
#undef SSTG_B23A

  float* red = (float*)&As2[0][0];
  float* red2 = red + 512;

  float ml[4][4];
#pragma unroll
  for (int mi = 0; mi < 4; ++mi)
#pragma unroll
    for (int rr = 0; rr < 4; ++rr)
      ml[mi][rr] = mask_lt[b * L_ + mt * 128 + wr * 64 + mi * 16 + l4 * 4 + rr];
  float mr[8];
#pragma unroll
  for (int ni = 0; ni < 8; ++ni)
    mr[ni] = mask_rt[b * L_ + wc * 128 + ni * 16 + l15];

#pragma unroll
  for (int mi = 0; mi < 4; ++mi)
#pragma unroll
    for (int ni = 0; ni < 8; ++ni)
#pragma unroll
      for (int rr = 0; rr < 4; ++rr)
        acc[mi][ni][rr] *= ml[mi][rr] * mr[ni];

#pragma unroll
  for (int mi = 0; mi < 4; ++mi)
#pragma unroll
    for (int rr = 0; rr < 4; ++rr) {
      float m = acc[mi][0][rr];
#pragma unroll
      for (int ni = 1; ni < 8; ++ni) m = fmaxf(m, acc[mi][ni][rr]);
      m = fmaxf(m, __shfl_xor(m, 1));
      m = fmaxf(m, __shfl_xor(m, 2));
      m = fmaxf(m, __shfl_xor(m, 4));
      m = fmaxf(m, __shfl_xor(m, 8));
      if (l15 == 0) red[(wr * 64 + mi * 16 + l4 * 4 + rr) * 4 + wc] = m;
    }
  __syncthreads();
  float mfull[4][4];
#pragma unroll
  for (int mi = 0; mi < 4; ++mi)
#pragma unroll
    for (int rr = 0; rr < 4; ++rr) {
      float4 v = *(const float4*)&red[(wr * 64 + mi * 16 + l4 * 4 + rr) * 4];
      mfull[mi][rr] = fmaxf(fmaxf(v.x, v.y), fmaxf(v.z, v.w));
    }

#pragma unroll
  for (int mi = 0; mi < 4; ++mi)
#pragma unroll
    for (int rr = 0; rr < 4; ++rr) {
      float s = 0.f;
#pragma unroll
      for (int ni = 0; ni < 8; ++ni) {
        float e = __expf(acc[mi][ni][rr] - mfull[mi][rr]);
        acc[mi][ni][rr] = e;
        s += e;
      }
      s += __shfl_xor(s, 1);
      s += __shfl_xor(s, 2);
      s += __shfl_xor(s, 4);
      s += __shfl_xor(s, 8);
      if (l15 == 0) red2[(wr * 64 + mi * 16 + l4 * 4 + rr) * 4 + wc] = s;
    }
  __syncthreads();

  float* obase = out + (size_t)b * L_ * L_ + (size_t)(mt * 128) * L_;
#pragma unroll
  for (int mi = 0; mi < 4; ++mi)
#pragma unroll
    for (int rr = 0; rr < 4; ++rr) {
      int row = wr * 64 + mi * 16 + l4 * 4 + rr;
      float4 v = *(const float4*)&red2[row * 4];
      float inv = 1.0f / (((v.x + v.y) + (v.z + v.w)));
      float scale = inv * ml[mi][rr];
#pragma unroll
      for (int ni = 0; ni < 8; ++ni) {
        int col = wc * 128 + ni * 16 + l15;
        obase[(size_t)row * L_ + col] = acc[mi][ni][rr] * scale * mr[ni];
      }
    }
}

extern "C" void kernel_launch(void* const* d_in, const int* in_sizes, int n_in,
                              void* d_out, int out_size, void* d_ws, size_t ws_size,
                              hipStream_t stream) {
  const float* reps_lt = (const float*)d_in[0];
  const float* reps_rt = (const float*)d_in[1];
  const float* mask_lt = (const float*)d_in[2];
  const float* mask_rt = (const float*)d_in[3];
  const float* attn_w1 = (const float*)d_in[4];
  const float* diag    = (const float*)d_in[5];
  float* out = (float*)d_out;

  unsigned short* wt = (unsigned short*)d_ws;           // 2 MB
  unsigned short* pb = wt + (size_t)H_ * A_;            // 128 MB
  unsigned short* xb = pb + (size_t)B_ * L_ * A_ * 2;   // 128 MB

  hipLaunchKernelGGL(wtrans_kernel, dim3(1024), dim3(256), 0, stream, attn_w1, wt);
  hipLaunchKernelGGL(cvt_kernel, dim3(8192), dim3(256), 0, stream,
                     reps_lt, reps_rt, xb);
  hipLaunchKernelGGL(proj8_kernel, dim3(1024), dim3(512), 0, stream,
                     xb, wt, diag, pb);
  hipLaunchKernelGGL(ssmax_kernel, dim3(256), dim3(512), 0, stream,
                     pb, mask_lt, mask_rt, out);
}

// Round 21
// 276.031 us; speedup vs baseline: 1.0973x; 1.0271x over previous
//
#include <hip/hip_runtime.h>
#include <hip/hip_bf16.h>

#define B_ 64
#define L_ 512
#define H_ 1024
#define A_ 1024

typedef short bf16x8 __attribute__((ext_vector_type(8)));
typedef float f32x4 __attribute__((ext_vector_type(4)));

__device__ __forceinline__ void gld16(const void* g, void* l) {
  __builtin_amdgcn_global_load_lds((const __attribute__((address_space(1))) void*)g,
                                   (__attribute__((address_space(3))) void*)l, 16, 0, 0);
}

__device__ __forceinline__ unsigned short f2bf(float f) {
  unsigned u = __builtin_bit_cast(unsigned, f);
  u = (u + 0x7fffu + ((u >> 16) & 1u)) >> 16;
  return (unsigned short)u;
}

__device__ __forceinline__ unsigned short cvtbf(float f) {
  __hip_bfloat16 b = __float2bfloat16(f);
  return __builtin_bit_cast(unsigned short, b);
}

__device__ __forceinline__ float fast_tanh(float x) {
  float e = __expf(2.f * x);
  float r = __builtin_amdgcn_rcpf(e + 1.f);
  return __builtin_fmaf(-2.f, r, 1.f);
}

// ---------- K-1: Xb = bf16(concat(Xlt, Xrt)), streaming ----------
__device__ __forceinline__ void cvt_chunk(const float* __restrict__ src,
                                          unsigned short* __restrict__ dst) {
  float4 v0 = ((const float4*)src)[0];
  float4 v1 = ((const float4*)src)[1];
  bf16x8 o;
  o[0] = (short)cvtbf(v0.x); o[1] = (short)cvtbf(v0.y);
  o[2] = (short)cvtbf(v0.z); o[3] = (short)cvtbf(v0.w);
  o[4] = (short)cvtbf(v1.x); o[5] = (short)cvtbf(v1.y);
  o[6] = (short)cvtbf(v1.z); o[7] = (short)cvtbf(v1.w);
  *(bf16x8*)dst = o;
}

__global__ __launch_bounds__(256) void cvt_kernel(const float* __restrict__ lt,
                                                  const float* __restrict__ rt,
                                                  unsigned short* __restrict__ xb) {
  const size_t NC = (size_t)B_ * L_ * H_ / 8;   // 4M chunks per tensor
  const size_t S  = NC / 2;                     // 2M = thread count
  size_t c0 = (size_t)blockIdx.x * 256 + threadIdx.x;
  cvt_chunk(lt + c0 * 8,        xb + c0 * 8);
  cvt_chunk(lt + (c0 + S) * 8,  xb + (c0 + S) * 8);
  cvt_chunk(rt + c0 * 8,        xb + (NC + c0) * 8);
  cvt_chunk(rt + (c0 + S) * 8,  xb + (NC + c0 + S) * 8);
}

// ---------- K0: Wt[a][h] = bf16(W[h][a]) ----------
__global__ __launch_bounds__(256) void wtrans_kernel(const float* __restrict__ W,
                                                     unsigned short* __restrict__ Wt) {
  __shared__ float tile[32][33];
  int tx = threadIdx.x & 31, ty = threadIdx.x >> 5;
  int a0 = (blockIdx.x & 31) << 5, h0 = (blockIdx.x >> 5) << 5;
#pragma unroll
  for (int i = 0; i < 4; ++i) {
    int h = ty + i * 8;
    tile[h][tx] = W[(size_t)(h0 + h) * A_ + a0 + tx];
  }
  __syncthreads();
#pragma unroll
  for (int i = 0; i < 4; ++i) {
    int a = ty + i * 8;
    Wt[(size_t)(a0 + a) * H_ + h0 + tx] = f2bf(tile[tx][a]);
  }
}

// ========== 8-phase conveyor, MINIMAL-BARRIER variant (4 per 2 K-tiles) =====
// Hazard audit: all W-A-R hazards are cross-buffer. Kept barriers:
//  (a) mid-half, before the B-staging phases: protects Bs[buf] writes vs
//      lagging waves' LOAD_BQ (their bq ds_reads are consumed by their own
//      phase-0 MFMA before they can reach this barrier);
//  (b) post-ckpt at each half end: per-wave vmcnt(4) confirms own stages,
//      barrier publishes to all waves (unchanged R14 semantics).
// All removed barriers separated phases reading the SAME buffer (read-read)
// while staging into the OTHER buffer -> no hazard. gld16 issue order is
// preserved between the remaining asm fences -> vmcnt counting intact.
#define STG_A(buf, h, kt) {                                                 \
    gld16(gA##h    + (kt) * 64, &As[buf][(h) * 8192 + lofs]);               \
    gld16(gA##h##b + (kt) * 64, &As[buf][(h) * 8192 + 4096 + lofs]); }
#define STG_B(buf, h, kt) {                                                 \
    gld16(gB##h    + (kt) * 64, &Bs[buf][(h) * 8192 + lofs]);               \
    gld16(gB##h##b + (kt) * 64, &Bs[buf][(h) * 8192 + 4096 + lofs]); }

#define LOAD_BQ(buf) { _Pragma("unroll") for (int ni = 0; ni < 4; ++ni) {   \
    int brow = wc * 64 + ni * 16 + l15;                                     \
    bq[ni][0] = *(const bf16x8*)&Bs[buf][brow * 64 + rd0];                  \
    bq[ni][1] = *(const bf16x8*)&Bs[buf][brow * 64 + rd1]; } }

// phase WITHOUT barriers: {aq ds_reads | stage -> MFMA cluster (setprio)}
#define PHASE_NB(q, buf, STAGE_OP) {                                        \
    bf16x8 aq0, aq1, aq2, aq3;                                              \
    { int ar = wr * 128 + (q) * 32 + l15;                                   \
      aq0 = *(const bf16x8*)&As[buf][ar * 64 + rd0];                        \
      aq1 = *(const bf16x8*)&As[buf][ar * 64 + rd1];                        \
      aq2 = *(const bf16x8*)&As[buf][(ar + 16) * 64 + rd0];                 \
      aq3 = *(const bf16x8*)&As[buf][(ar + 16) * 64 + rd1]; }               \
    STAGE_OP;                                                               \
    __builtin_amdgcn_s_setprio(1);                                          \
    _Pragma("unroll") for (int ni = 0; ni < 4; ++ni) {                      \
      acc[(q)*2][ni] = __builtin_amdgcn_mfma_f32_16x16x32_bf16(             \
          aq0, bq[ni][0], acc[(q)*2][ni], 0, 0, 0);                         \
      acc[(q)*2][ni] = __builtin_amdgcn_mfma_f32_16x16x32_bf16(             \
          aq1, bq[ni][1], acc[(q)*2][ni], 0, 0, 0);                         \
      acc[(q)*2+1][ni] = __builtin_amdgcn_mfma_f32_16x16x32_bf16(           \
          aq2, bq[ni][0], acc[(q)*2+1][ni], 0, 0, 0);                       \
      acc[(q)*2+1][ni] = __builtin_amdgcn_mfma_f32_16x16x32_bf16(           \
          aq3, bq[ni][1], acc[(q)*2+1][ni], 0, 0, 0); }                     \
    __builtin_amdgcn_s_setprio(0); }

#define CONV_ITER(kt1, kt2, kt3) {                                          \
    LOAD_BQ(0);                                                             \
    PHASE_NB(0, 0, STG_A(1, 0, kt1));                                       \
    PHASE_NB(1, 0, STG_A(1, 1, kt1));                                       \
    asm volatile("s_barrier" ::: "memory");                                 \
    PHASE_NB(2, 0, STG_B(0, 0, kt2));                                       \
    PHASE_NB(3, 0, STG_B(0, 1, kt2));                                       \
    asm volatile("s_waitcnt vmcnt(4)" ::: "memory");                        \
    asm volatile("s_barrier" ::: "memory");                                 \
    LOAD_BQ(1);                                                             \
    PHASE_NB(0, 1, STG_A(0, 0, kt2));                                       \
    PHASE_NB(1, 1, STG_A(0, 1, kt2));                                       \
    asm volatile("s_barrier" ::: "memory");                                 \
    PHASE_NB(2, 1, STG_B(1, 0, kt3));                                       \
    PHASE_NB(3, 1, STG_B(1, 1, kt3));                                       \
    asm volatile("s_waitcnt vmcnt(4)" ::: "memory");                        \
    asm volatile("s_barrier" ::: "memory"); }

#define CONVEYOR_LIT()                                                      \
  STG_B(0, 0, 0); STG_B(0, 1, 0);                                           \
  STG_A(0, 0, 0); STG_A(0, 1, 0);                                           \
  STG_B(1, 0, 1); STG_B(1, 1, 1);                                           \
  asm volatile("s_waitcnt vmcnt(4)" ::: "memory");                          \
  asm volatile("s_barrier" ::: "memory");                                   \
  CONV_ITER(1, 2, 3)   CONV_ITER(3, 4, 5)   CONV_ITER(5, 6, 7)              \
  CONV_ITER(7, 8, 9)   CONV_ITER(9, 10, 11) CONV_ITER(11, 12, 13)           \
  CONV_ITER(13, 14, 15) CONV_ITER(15, 0, 1)

// ---------- K1: 256x256 8-phase proj: Pb = bf16(tanh(Xb@Wt^T)[*diag]) ------
__global__ __launch_bounds__(512, 2) void proj8_kernel(
    const unsigned short* __restrict__ Xb, const unsigned short* __restrict__ Wt,
    const float* __restrict__ diag, unsigned short* __restrict__ Pb) {
  __shared__ unsigned short As[2][256 * 64];
  __shared__ unsigned short Bs[2][256 * 64];
  int t = threadIdx.x;
  int lane = t & 63, wave = t >> 6;
  int wr = wave >> 2, wc = wave & 3;
  int l15 = lane & 15, l4 = lane >> 4;

  int bid = (int)blockIdx.x;           // 1024 blocks, XCD swizzle
  int x = bid & 7, k = bid >> 3;
  int mt = x + 8 * (k >> 2);           // [0,256)
  int nt = k & 3;
  int mrow0 = mt << 8, ncol0 = nt << 8;
  int isLt = (mt < 128);

  int rs = t >> 3, ss = t & 7;
  const unsigned short* gA0 = Xb + (size_t)(mrow0 + rs) * H_ + ((ss ^ (rs & 7)) << 3);
  const unsigned short* gA0b = gA0 + (size_t)64 * H_;
  const unsigned short* gA1  = gA0 + (size_t)128 * H_;
  const unsigned short* gA1b = gA0 + (size_t)192 * H_;
  const unsigned short* gB0 = Wt + (size_t)(ncol0 + rs) * H_ + ((ss ^ (rs & 7)) << 3);
  const unsigned short* gB0b = gB0 + (size_t)64 * H_;
  const unsigned short* gB1  = gB0 + (size_t)128 * H_;
  const unsigned short* gB1b = gB0 + (size_t)192 * H_;
  int lofs = (rs * 8 + ss) * 8;

  int rd0 = (l4 ^ (l15 & 7)) * 8;
  int rd1 = ((4 + l4) ^ (l15 & 7)) * 8;

  f32x4 acc[8][4] = {};
  bf16x8 bq[4][2];

  CONVEYOR_LIT();

#pragma unroll
  for (int mi = 0; mi < 8; ++mi) {
#pragma unroll
    for (int ni = 0; ni < 4; ++ni) {
      int col = ncol0 + wc * 64 + ni * 16 + l15;
      float d = isLt ? diag[col] : 1.0f;
#pragma unroll
      for (int rr = 0; rr < 4; ++rr) {
        int row = mrow0 + wr * 128 + mi * 16 + l4 * 4 + rr;
        Pb[(size_t)row * A_ + col] = f2bf(fast_tanh(acc[mi][ni][rr]) * d);
      }
    }
  }
}

// ---------- K2: fused score+softmax (R17, proven) ----------
__global__ __launch_bounds__(512) void ssmax_kernel(
    const unsigned short* __restrict__ Pb,
    const float* __restrict__ mask_lt, const float* __restrict__ mask_rt,
    float* __restrict__ out) {
  __shared__ unsigned short As2[3][128 * 32];  // 3 x 8 KB
  __shared__ unsigned short Bs2[3][512 * 32];  // 3 x 32 KB
  int t = threadIdx.x;
  int lane = t & 63, wave = t >> 6;
  int wr = wave >> 2, wc = wave & 3;
  int l15 = lane & 15, l4 = lane >> 4;

  int bid = (int)blockIdx.x;           // 256 blocks
  int g = (bid & 7) * 32 + (bid >> 3);
  int b = g >> 2, mt = g & 3;

  int arow0 = b * L_ + mt * 128;
  int brow0 = B_ * L_ + b * L_;

  int ra = t >> 2, ca = t & 3;
  const unsigned short* gA = Pb + (size_t)(arow0 + ra) * H_ + ((ca ^ ((ra >> 1) & 3)) << 3);
  const unsigned short* gBu0; const unsigned short* gBu1;
  const unsigned short* gBu2; const unsigned short* gBu3;
  int bd0, bd1, bd2, bd3;
  {
    int ci, r, c;
    ci = t;        r = ci >> 2; c = ci & 3;
    gBu0 = Pb + (size_t)(brow0 + r) * H_ + ((c ^ ((r >> 1) & 3)) << 3); bd0 = ci * 8;
    ci = 512 + t;  r = ci >> 2; c = ci & 3;
    gBu1 = Pb + (size_t)(brow0 + r) * H_ + ((c ^ ((r >> 1) & 3)) << 3); bd1 = ci * 8;
    ci = 1024 + t; r = ci >> 2; c = ci & 3;
    gBu2 = Pb + (size_t)(brow0 + r) * H_ + ((c ^ ((r >> 1) & 3)) << 3); bd2 = ci * 8;
    ci = 1536 + t; r = ci >> 2; c = ci & 3;
    gBu3 = Pb + (size_t)(brow0 + r) * H_ + ((c ^ ((r >> 1) & 3)) << 3); bd3 = ci * 8;
  }
  int rd = (l4 ^ ((l15 >> 1) & 3)) * 8;

#define SSTG_B01(buf, kt_) { int ko = (kt_) * 32;                  \
    gld16(gBu0 + ko, &Bs2[buf][bd0]); gld16(gBu1 + ko, &Bs2[buf][bd1]); }
#define SSTG_B23A(buf, kt_) { int ko = (kt_) * 32;                 \
    gld16(gBu2 + ko, &Bs2[buf][bd2]); gld16(gBu3 + ko, &Bs2[buf][bd3]); \
    gld16(gA + ko, &As2[buf][t * 8]); }

  f32x4 acc[4][8] = {};

  SSTG_B01(0, 0); SSTG_B23A(0, 0);
  SSTG_B01(1, 1); SSTG_B23A(1, 1);
  asm volatile("s_waitcnt vmcnt(5)" ::: "memory");
  asm volatile("s_barrier" ::: "memory");

#pragma unroll 1
  for (int j = 0; j < 32; ++j) {
    int buf = j - (j / 3) * 3;
    int nb = buf + 2; if (nb >= 3) nb -= 3;
    bool st = (j <= 29);
    const unsigned short* Ac = As2[buf];
    const unsigned short* Bc = Bs2[buf];

    bf16x8 aq[4], bq[4];
#pragma unroll
    for (int mi = 0; mi < 4; ++mi)
      aq[mi] = *(const bf16x8*)&Ac[(wr * 64 + mi * 16 + l15) * 32 + rd];
#pragma unroll
    for (int ni = 0; ni < 4; ++ni)
      bq[ni] = *(const bf16x8*)&Bc[(wc * 128 + ni * 16 + l15) * 32 + rd];
    if (st) SSTG_B01(nb, j + 2);
    asm volatile("s_barrier" ::: "memory");
    __builtin_amdgcn_s_setprio(1);
#pragma unroll
    for (int mi = 0; mi < 4; ++mi)
#pragma unroll
      for (int ni = 0; ni < 4; ++ni)
        acc[mi][ni] = __builtin_amdgcn_mfma_f32_16x16x32_bf16(aq[mi], bq[ni], acc[mi][ni], 0, 0, 0);
    __builtin_amdgcn_s_setprio(0);
    asm volatile("s_barrier" ::: "memory");

#pragma unroll
    for (int ni = 0; ni < 4; ++ni)
      bq[ni] = *(const bf16x8*)&Bc[(wc * 128 + 64 + ni * 16 + l15) * 32 + rd];
    if (st) SSTG_B23A(nb, j + 2);
    asm volatile("s_barrier" ::: "memory");
    __builtin_amdgcn_s_setprio(1);
#pragma unroll
    for (int mi = 0; mi < 4; ++mi)
#pragma unroll
      for (int ni = 0; ni < 4; ++ni)
        acc[mi][ni + 4] = __builtin_amdgcn_mfma_f32_16x16x32_bf16(aq[mi], bq[ni], acc[mi][ni + 4], 0, 0, 0);
    __builtin_amdgcn_s_setprio(0);
    if (j < 30)
      asm volatile("s_waitcnt vmcnt(5)" ::: "memory");
    else
      asm volatile("s_waitcnt vmcnt(0)" ::: "memory");
    asm volatile("s_barrier" ::: "memory");
  }
#undef SSTG_B01
#undef SSTG_B23A

  float* red = (float*)&As2[0][0];
  float* red2 = red + 512;

  float ml[4][4];
#pragma unroll
  for (int mi = 0; mi < 4; ++mi)
#pragma unroll
    for (int rr = 0; rr < 4; ++rr)
      ml[mi][rr] = mask_lt[b * L_ + mt * 128 + wr * 64 + mi * 16 + l4 * 4 + rr];
  float mr[8];
#pragma unroll
  for (int ni = 0; ni < 8; ++ni)
    mr[ni] = mask_rt[b * L_ + wc * 128 + ni * 16 + l15];

#pragma unroll
  for (int mi = 0; mi < 4; ++mi)
#pragma unroll
    for (int ni = 0; ni < 8; ++ni)
#pragma unroll
      for (int rr = 0; rr < 4; ++rr)
        acc[mi][ni][rr] *= ml[mi][rr] * mr[ni];

#pragma unroll
  for (int mi = 0; mi < 4; ++mi)
#pragma unroll
    for (int rr = 0; rr < 4; ++rr) {
      float m = acc[mi][0][rr];
#pragma unroll
      for (int ni = 1; ni < 8; ++ni) m = fmaxf(m, acc[mi][ni][rr]);
      m = fmaxf(m, __shfl_xor(m, 1));
      m = fmaxf(m, __shfl_xor(m, 2));
      m = fmaxf(m, __shfl_xor(m, 4));
      m = fmaxf(m, __shfl_xor(m, 8));
      if (l15 == 0) red[(wr * 64 + mi * 16 + l4 * 4 + rr) * 4 + wc] = m;
    }
  __syncthreads();
  float mfull[4][4];
#pragma unroll
  for (int mi = 0; mi < 4; ++mi)
#pragma unroll
    for (int rr = 0; rr < 4; ++rr) {
      float4 v = *(const float4*)&red[(wr * 64 + mi * 16 + l4 * 4 + rr) * 4];
      mfull[mi][rr] = fmaxf(fmaxf(v.x, v.y), fmaxf(v.z, v.w));
    }

#pragma unroll
  for (int mi = 0; mi < 4; ++mi)
#pragma unroll
    for (int rr = 0; rr < 4; ++rr) {
      float s = 0.f;
#pragma unroll
      for (int ni = 0; ni < 8; ++ni) {
        float e = __expf(acc[mi][ni][rr] - mfull[mi][rr]);
        acc[mi][ni][rr] = e;
        s += e;
      }
      s += __shfl_xor(s, 1);
      s += __shfl_xor(s, 2);
      s += __shfl_xor(s, 4);
      s += __shfl_xor(s, 8);
      if (l15 == 0) red2[(wr * 64 + mi * 16 + l4 * 4 + rr) * 4 + wc] = s;
    }
  __syncthreads();

  float* obase = out + (size_t)b * L_ * L_ + (size_t)(mt * 128) * L_;
#pragma unroll
  for (int mi = 0; mi < 4; ++mi)
#pragma unroll
    for (int rr = 0; rr < 4; ++rr) {
      int row = wr * 64 + mi * 16 + l4 * 4 + rr;
      float4 v = *(const float4*)&red2[row * 4];
      float inv = 1.0f / (((v.x + v.y) + (v.z + v.w)));
      float scale = inv * ml[mi][rr];
#pragma unroll
      for (int ni = 0; ni < 8; ++ni) {
        int col = wc * 128 + ni * 16 + l15;
        obase[(size_t)row * L_ + col] = acc[mi][ni][rr] * scale * mr[ni];
      }
    }
}

extern "C" void kernel_launch(void* const* d_in, const int* in_sizes, int n_in,
                              void* d_out, int out_size, void* d_ws, size_t ws_size,
                              hipStream_t stream) {
  const float* reps_lt = (const float*)d_in[0];
  const float* reps_rt = (const float*)d_in[1];
  const float* mask_lt = (const float*)d_in[2];
  const float* mask_rt = (const float*)d_in[3];
  const float* attn_w1 = (const float*)d_in[4];
  const float* diag    = (const float*)d_in[5];
  float* out = (float*)d_out;

  unsigned short* wt = (unsigned short*)d_ws;           // 2 MB
  unsigned short* pb = wt + (size_t)H_ * A_;            // 128 MB
  unsigned short* xb = pb + (size_t)B_ * L_ * A_ * 2;   // 128 MB

  hipLaunchKernelGGL(wtrans_kernel, dim3(1024), dim3(256), 0, stream, attn_w1, wt);
  hipLaunchKernelGGL(cvt_kernel, dim3(8192), dim3(256), 0, stream,
                     reps_lt, reps_rt, xb);
  hipLaunchKernelGGL(proj8_kernel, dim3(1024), dim3(512), 0, stream,
                     xb, wt, diag, pb);
  hipLaunchKernelGGL(ssmax_kernel, dim3(256), dim3(512), 0, stream,
                     pb, mask_lt, mask_rt, out);
}